// Round 12
// baseline (438.506 us; speedup 1.0000x reference)
//
#include <hip/hip_runtime.h>

constexpr int NB = 1024;   // graphs
constexpr int NN = 64;     // nodes per graph
constexpr int ND = 128;    // feature dim (D == G == 128)
constexpr int NE = 512;    // edges per graph
constexpr int FEAT_F = 12288;  // 3*16*16*16

typedef __attribute__((ext_vector_type(8))) short short8v;   // 8 bf16 (4 VGPRs)
typedef __attribute__((ext_vector_type(4))) float f32x4;
typedef __fp16 h2v __attribute__((ext_vector_type(2)));      // matches cvt_pkrtz/fdot2

__device__ inline ushort f2bf(float x) {                      // fp32 -> bf16 RNE
    unsigned u = __float_as_uint(x);
    u += 0x7FFFu + ((u >> 16) & 1u);
    return (ushort)(u >> 16);
}

// ---------------- build normalized adjacency Â (bf16) per (graph, side) ----------------
__global__ __launch_bounds__(256)
void adj_kernel(const int* __restrict__ esq, const int* __restrict__ edq,
                const int* __restrict__ esc, const int* __restrict__ edc,
                ushort* __restrict__ Aq, ushort* __restrict__ Ac)
{
    __shared__ float A[NN * NN];
    __shared__ float dis[NN];
    const int b = blockIdx.x, side = blockIdx.y, tid = threadIdx.x;
    const int* es = side ? esc : esq;
    const int* ed = side ? edc : edq;
    ushort* Aout = side ? Ac : Aq;

    for (int i = tid; i < NN * NN; i += 256) A[i] = 0.f;
    __syncthreads();
    for (int e = tid; e < NE; e += 256) {
        const int s = es[b * NE + e] & (NN - 1);
        const int d = ed[b * NE + e] & (NN - 1);
        atomicAdd(&A[d * NN + s], 1.0f);
    }
    __syncthreads();
    if (tid < NN) {
        float sum = 1.0f;                       // self loop
        for (int s = 0; s < NN; s++) sum += A[tid * NN + s];
        dis[tid] = rsqrtf(sum);
    }
    __syncthreads();
    for (int i = tid; i < NN * NN; i += 256) {
        const int d = i >> 6, s = i & 63;
        float v = A[i];
        if (d == s) v += 1.0f;                  // self loop
        Aout[(size_t)b * (NN * NN) + i] = f2bf(dis[d] * v * dis[s]);
    }
}

// ---------------- cast+transpose gcn weights: wtb[l][f][k] = bf16(W_l[k][f]) ----------------
__global__ __launch_bounds__(256)
void castw_kernel(const float* __restrict__ w0, const float* __restrict__ w1,
                  const float* __restrict__ w2, ushort* __restrict__ wtb)
{
    const float* W = blockIdx.x == 0 ? w0 : (blockIdx.x == 1 ? w1 : w2);
    ushort* out = wtb + (size_t)blockIdx.x * ND * ND;
    for (int i = threadIdx.x; i < ND * ND; i += 256) {
        const int f = i >> 7, k = i & 127;
        out[i] = f2bf(W[k * ND + f]);
    }
}

// ---------------- GCN layer via MFMA, LDS-less operand reads ----------------
// A-fragments (H rows, Â rows) are wave-private -> per-lane direct global reads.
// W^T fragments direct from global (L2-hot, shared by all blocks). Only mT
// (cross-wave M^T exchange) lives in LDS -> 17.4KB, high occupancy, 1 barrier.
__global__ __launch_bounds__(256)
void gcn_mfma_kernel(const void* __restrict__ hq_in, const void* __restrict__ hc_in,
                     const ushort* __restrict__ Aqb, const ushort* __restrict__ Acb,
                     const ushort* __restrict__ wt_l, const float* __restrict__ bias,
                     ushort* __restrict__ outq, ushort* __restrict__ outc, int first)
{
    __shared__ ushort mT[128][68];     // M^T [f][s], 17.4KB

    const int b = blockIdx.x, side = blockIdx.y, tid = threadIdx.x;
    const int lane = tid & 63, w = tid >> 6;
    const int q = lane >> 4, rf = lane & 15;

    const ushort* Ab = (side ? Acb : Aqb) + (size_t)b * 4096;
    ushort* outp = (side ? outc : outq) + (size_t)b * 8192;

    // ---- A-fragments for mm1: row 16w+rf of H, relu'd ----
    short8v af[4];
    if (first) {
        const float* hin = (const float*)(side ? hc_in : hq_in)
                         + (size_t)b * 8192 + (16 * w + rf) * 128;
        #pragma unroll
        for (int ks = 0; ks < 4; ks++) {
            const float4 v0 = *(const float4*)&hin[32 * ks + 8 * q];
            const float4 v1 = *(const float4*)&hin[32 * ks + 8 * q + 4];
            short8v v;
            v[0] = (short)f2bf(v0.x); v[1] = (short)f2bf(v0.y);
            v[2] = (short)f2bf(v0.z); v[3] = (short)f2bf(v0.w);
            v[4] = (short)f2bf(v1.x); v[5] = (short)f2bf(v1.y);
            v[6] = (short)f2bf(v1.z); v[7] = (short)f2bf(v1.w);
            af[ks] = v;
        }
    } else {
        const ushort* hin = (const ushort*)(side ? hc_in : hq_in)
                          + (size_t)b * 8192 + (16 * w + rf) * 128;
        #pragma unroll
        for (int ks = 0; ks < 4; ks++) {
            short8v v = *(const short8v*)&hin[32 * ks + 8 * q];
            #pragma unroll
            for (int e = 0; e < 8; e++) {
                const ushort u = (ushort)v[e];
                v[e] = (short)((u & 0x8000u) ? 0u : u);   // relu(bf16)
            }
            af[ks] = v;
        }
    }

    // ---- mm1: M = H @ W ; B-fragments direct from global W^T ----
    {
        f32x4 acc1[8];
        #pragma unroll
        for (int cb = 0; cb < 8; cb++) acc1[cb] = f32x4{0.f, 0.f, 0.f, 0.f};
        #pragma unroll
        for (int cb = 0; cb < 8; cb++)
            #pragma unroll
            for (int ks = 0; ks < 4; ks++) {
                const short8v bf = *(const short8v*)&wt_l[(size_t)(16 * cb + rf) * 128 + 32 * ks + 8 * q];
                acc1[cb] = __builtin_amdgcn_mfma_f32_16x16x32_bf16(af[ks], bf, acc1[cb], 0, 0, 0);
            }
        // C layout: col(f)=rf, row(s)=4q+r -> mT[f][s]
        #pragma unroll
        for (int cb = 0; cb < 8; cb++)
            *(ushort4*)&mT[16 * cb + rf][16 * w + 4 * q] =
                make_ushort4(f2bf(acc1[cb][0]), f2bf(acc1[cb][1]), f2bf(acc1[cb][2]), f2bf(acc1[cb][3]));
    }
    __syncthreads();

    // ---- mm2: out = Â @ M + bias ; Â-fragments direct from global ----
    {
        short8v af2[2];
        #pragma unroll
        for (int ks = 0; ks < 2; ks++)
            af2[ks] = *(const short8v*)&Ab[(size_t)(16 * w + rf) * 64 + 32 * ks + 8 * q];
        f32x4 acc2[8];
        #pragma unroll
        for (int cb = 0; cb < 8; cb++) acc2[cb] = f32x4{0.f, 0.f, 0.f, 0.f};
        #pragma unroll
        for (int cb = 0; cb < 8; cb++)
            #pragma unroll
            for (int ks = 0; ks < 2; ks++) {
                const short8v bf2 = *(const short8v*)&mT[16 * cb + rf][32 * ks + 8 * q];
                acc2[cb] = __builtin_amdgcn_mfma_f32_16x16x32_bf16(af2[ks], bf2, acc2[cb], 0, 0, 0);
            }
        #pragma unroll
        for (int cb = 0; cb < 8; cb++) {
            const float bb = bias[16 * cb + rf];
            #pragma unroll
            for (int r = 0; r < 4; r++)
                outp[(16 * w + 4 * q + r) * 128 + 16 * cb + rf] = f2bf(acc2[cb][r] + bb);
        }
    }
}

// ---------------- fused sims + conv1 (f16 dot2) + conv2 (bf16 MFMA) ----------------
// Per (b,l): S = hq_l[b] @ hc_l[b]^T via MFMA (operands direct from global),
// written into padded img LDS; then conv1+pool -> p1b; conv2 MFMA -> featb.
__global__ __launch_bounds__(256)
void conv_kernel(const ushort* __restrict__ hq0, const ushort* __restrict__ hc0,
                 const ushort* __restrict__ hq1, const ushort* __restrict__ hc1,
                 const ushort* __restrict__ hq2, const ushort* __restrict__ hc2,
                 const float* __restrict__ c1w, const float* __restrict__ c1b,
                 const float* __restrict__ c2w, const float* __restrict__ c2b,
                 ushort* __restrict__ featb)
{
    __shared__ float img[68 * 68];          // 18.5KB, 64x64 padded by 2
    __shared__ ushort p1b[36 * 36 * 8];     // 20.7KB
    __shared__ ushort w2s[16][232];         // 7.4KB

    const int b = blockIdx.x, l = blockIdx.y, tid = threadIdx.x;
    const int lane = tid & 63, wid = tid >> 6;
    const int q = lane >> 4, rf = lane & 15;

    const ushort* hq = (l == 0 ? hq0 : (l == 1 ? hq1 : hq2)) + (size_t)b * 8192;
    const ushort* hc = (l == 0 ? hc0 : (l == 1 ? hc1 : hc2)) + (size_t)b * 8192;

    for (int i = tid; i < 68 * 68; i += 256) img[i] = 0.f;
    for (int i = tid; i < 36 * 36 * 8 / 2; i += 256) ((uint*)p1b)[i] = 0u;
    for (int i = tid; i < 16 * 224; i += 256) {
        const int co = i / 224, k = i - co * 224;
        const int tap = k >> 3, ci = k & 7;
        w2s[co][k] = (tap < 25) ? f2bf(c2w[l * 3200 + co * 200 + ci * 25 + tap])
                                : (ushort)0;
    }
    __syncthreads();

    // ---- sims MFMA: wave computes S rows 16*wid..16*wid+15, writes img interior ----
    {
        short8v afq[4];
        #pragma unroll
        for (int ks = 0; ks < 4; ks++)
            afq[ks] = *(const short8v*)&hq[(size_t)(16 * wid + rf) * 128 + 32 * ks + 8 * q];
        #pragma unroll
        for (int cb = 0; cb < 4; cb++) {
            f32x4 acc = {0.f, 0.f, 0.f, 0.f};
            #pragma unroll
            for (int ks = 0; ks < 4; ks++) {
                const short8v bf = *(const short8v*)&hc[(size_t)(16 * cb + rf) * 128 + 32 * ks + 8 * q];
                acc = __builtin_amdgcn_mfma_f32_16x16x32_bf16(afq[ks], bf, acc, 0, 0, 0);
            }
            // C layout: row(y)=16*wid+4q+r, col(x)=16*cb+rf
            #pragma unroll
            for (int r = 0; r < 4; r++)
                img[(16 * wid + 4 * q + r + 2) * 68 + (16 * cb + rf + 2)] = acc[r];
        }
    }
    __syncthreads();

    // ---- conv1: thread owns 2x2 POOLED outputs at (2by+jy, 2bx+jx); 8x8 patch ----
    {
        const int by = tid >> 4, bx = tid & 15;
        float mv[2][2][8];                   // [jy][jx][cout] pooled+relu'd results
#if __has_builtin(__builtin_amdgcn_fdot2)
        h2v pe[8][4], po[8][4];
        #pragma unroll
        for (int r = 0; r < 8; r++) {
            float x[8];
            #pragma unroll
            for (int c2 = 0; c2 < 4; c2++) {
                const float2 v = *(const float2*)&img[(4 * by + r) * 68 + 4 * bx + 2 * c2];
                x[2 * c2] = v.x; x[2 * c2 + 1] = v.y;
            }
            #pragma unroll
            for (int m = 0; m < 4; m++) {
                pe[r][m] = __builtin_amdgcn_cvt_pkrtz(x[2 * m], x[2 * m + 1]);
                po[r][m] = __builtin_amdgcn_cvt_pkrtz(x[2 * m + 1], (m < 3) ? x[2 * m + 2] : x[7]);
            }
        }
        for (int c = 0; c < 8; c++) {
            h2v wp[5][3];
            #pragma unroll
            for (int ky = 0; ky < 5; ky++) {
                const float w0 = c1w[l * 200 + c * 25 + 5 * ky];
                const float w1 = c1w[l * 200 + c * 25 + 5 * ky + 1];
                const float w2 = c1w[l * 200 + c * 25 + 5 * ky + 2];
                const float w3 = c1w[l * 200 + c * 25 + 5 * ky + 3];
                const float w4 = c1w[l * 200 + c * 25 + 5 * ky + 4];
                wp[ky][0] = __builtin_amdgcn_cvt_pkrtz(w0, w1);
                wp[ky][1] = __builtin_amdgcn_cvt_pkrtz(w2, w3);
                wp[ky][2] = __builtin_amdgcn_cvt_pkrtz(w4, 0.f);
            }
            const float bb = c1b[l * 8 + c];
            #pragma unroll
            for (int jy = 0; jy < 2; jy++)
                #pragma unroll
                for (int jx = 0; jx < 2; jx++) {
                    float mm = 0.f;
                    #pragma unroll
                    for (int dy = 0; dy < 2; dy++)
                        #pragma unroll
                        for (int dx = 0; dx < 2; dx++) {
                            const int Y = 2 * jy + dy, X = 2 * jx + dx, m0 = X >> 1;
                            float a = bb;
                            #pragma unroll
                            for (int ky = 0; ky < 5; ky++) {
                                if (X & 1) {
                                    a = __builtin_amdgcn_fdot2(po[Y + ky][m0],     wp[ky][0], a, false);
                                    a = __builtin_amdgcn_fdot2(po[Y + ky][m0 + 1], wp[ky][1], a, false);
                                    a = __builtin_amdgcn_fdot2(po[Y + ky][m0 + 2], wp[ky][2], a, false);
                                } else {
                                    a = __builtin_amdgcn_fdot2(pe[Y + ky][m0],     wp[ky][0], a, false);
                                    a = __builtin_amdgcn_fdot2(pe[Y + ky][m0 + 1], wp[ky][1], a, false);
                                    a = __builtin_amdgcn_fdot2(pe[Y + ky][m0 + 2], wp[ky][2], a, false);
                                }
                            }
                            mm = fmaxf(mm, a);
                        }
                    mv[jy][jx][c] = mm;
                }
        }
#else
        float pt[8][8];
        #pragma unroll
        for (int r = 0; r < 8; r++)
            #pragma unroll
            for (int c2 = 0; c2 < 4; c2++) {
                const float2 v = *(const float2*)&img[(4 * by + r) * 68 + 4 * bx + 2 * c2];
                pt[r][2 * c2] = v.x; pt[r][2 * c2 + 1] = v.y;
            }
        for (int c = 0; c < 8; c++) {
            float wr[25];
            #pragma unroll
            for (int t = 0; t < 25; t++) wr[t] = c1w[l * 200 + c * 25 + t];
            const float bb = c1b[l * 8 + c];
            #pragma unroll
            for (int jy = 0; jy < 2; jy++)
                #pragma unroll
                for (int jx = 0; jx < 2; jx++) {
                    float mm = 0.f;
                    #pragma unroll
                    for (int dy = 0; dy < 2; dy++)
                        #pragma unroll
                        for (int dx = 0; dx < 2; dx++) {
                            float a = bb;
                            #pragma unroll
                            for (int ky = 0; ky < 5; ky++)
                                #pragma unroll
                                for (int kx = 0; kx < 5; kx++)
                                    a += pt[2 * jy + dy + ky][2 * jx + dx + kx] * wr[ky * 5 + kx];
                            mm = fmaxf(mm, a);
                        }
                    mv[jy][jx][c] = mm;
                }
        }
#endif
        #pragma unroll
        for (int jy = 0; jy < 2; jy++)
            #pragma unroll
            for (int jx = 0; jx < 2; jx++) {
                const int pos = (2 * by + jy + 2) * 36 + (2 * bx + jx + 2);
                *(ushort4*)&p1b[pos * 8] =
                    make_ushort4(f2bf(mv[jy][jx][0]), f2bf(mv[jy][jx][1]),
                                 f2bf(mv[jy][jx][2]), f2bf(mv[jy][jx][3]));
                *(ushort4*)&p1b[pos * 8 + 4] =
                    make_ushort4(f2bf(mv[jy][jx][4]), f2bf(mv[jy][jx][5]),
                                 f2bf(mv[jy][jx][6]), f2bf(mv[jy][jx][7]));
            }
    }
    __syncthreads();

    // ---- conv2 MFMA: wave handles y-pairs r = wid+4t ----
    short8v bf[7];
    #pragma unroll
    for (int ks = 0; ks < 7; ks++)
        bf[ks] = *(const short8v*)&w2s[rf][32 * ks + 8 * q];
    const float bb2 = c2b[l * 16 + rf];

    for (int t = 0; t < 4; t++) {
        const int r = wid + 4 * t;
        f32x4 acc00 = {0.f,0.f,0.f,0.f}, acc01 = acc00, acc10 = acc00, acc11 = acc00;
        #pragma unroll
        for (int ks = 0; ks < 7; ks++) {
            const int tap = 4 * ks + q;
            const int dy = tap / 5, dx = tap - 5 * dy;
            const bool dum = tap >= 25;
            const int row0 = dum ? 35 : (2 * r + dy);
            const int row1 = dum ? 35 : (2 * r + 1 + dy);
            const int cb   = (dum ? 0 : dx) + rf;
            const short8v a00 = *(const short8v*)&p1b[(row0 * 36 + cb) * 8];
            const short8v a01 = *(const short8v*)&p1b[(row0 * 36 + cb + 16) * 8];
            const short8v a10 = *(const short8v*)&p1b[(row1 * 36 + cb) * 8];
            const short8v a11 = *(const short8v*)&p1b[(row1 * 36 + cb + 16) * 8];
            acc00 = __builtin_amdgcn_mfma_f32_16x16x32_bf16(a00, bf[ks], acc00, 0, 0, 0);
            acc01 = __builtin_amdgcn_mfma_f32_16x16x32_bf16(a01, bf[ks], acc01, 0, 0, 0);
            acc10 = __builtin_amdgcn_mfma_f32_16x16x32_bf16(a10, bf[ks], acc10, 0, 0, 0);
            acc11 = __builtin_amdgcn_mfma_f32_16x16x32_bf16(a11, bf[ks], acc11, 0, 0, 0);
        }
        const float v0 = fmaxf(fmaxf(fmaxf(acc00[0], acc00[1]), fmaxf(acc10[0], acc10[1])) + bb2, 0.f);
        const float v1 = fmaxf(fmaxf(fmaxf(acc00[2], acc00[3]), fmaxf(acc10[2], acc10[3])) + bb2, 0.f);
        const float v2 = fmaxf(fmaxf(fmaxf(acc01[0], acc01[1]), fmaxf(acc11[0], acc11[1])) + bb2, 0.f);
        const float v3 = fmaxf(fmaxf(fmaxf(acc01[2], acc01[3]), fmaxf(acc11[2], acc11[3])) + bb2, 0.f);
        const size_t base = (size_t)b * FEAT_F + ((size_t)l * 16 + rf) * 256 + r * 16;
        featb[base + 2 * q]         = f2bf(v0);
        featb[base + 2 * q + 1]     = f2bf(v1);
        featb[base + 8 + 2 * q]     = f2bf(v2);
        featb[base + 8 + 2 * q + 1] = f2bf(v3);
    }
}

// ---------------- cast + transpose lw (12288x512) -> lwT bf16 (512x12288) ----------------
__global__ __launch_bounds__(256)
void cast_lwT_kernel(const float* __restrict__ lw, ushort* __restrict__ lwT)
{
    __shared__ ushort t[32][34];
    const int kb = blockIdx.x * 32, nb2 = blockIdx.y * 32;
    const int x = threadIdx.x & 31, y = threadIdx.x >> 5;
    #pragma unroll
    for (int j = 0; j < 4; j++) {
        const int yy = y + 8 * j;
        t[x][yy] = f2bf(lw[(size_t)(kb + yy) * 512 + nb2 + x]);
    }
    __syncthreads();
    #pragma unroll
    for (int j = 0; j < 4; j++) {
        const int yy = y + 8 * j;
        lwT[(size_t)(nb2 + yy) * FEAT_F + kb + x] = t[yy][x];
    }
}

// ---------------- linear via MFMA: hacc8[kz] = feat_tile @ lw_tile ----------------
__global__ __launch_bounds__(256)
void lin_mfma_kernel(const ushort* __restrict__ featb, const ushort* __restrict__ lwT,
                     float* __restrict__ hacc8)
{
    __shared__ ushort a_s[64][40];
    __shared__ ushort b_s[64][40];
    const int nb = blockIdx.x, mb = blockIdx.y, kz = blockIdx.z;
    const int tid = threadIdx.x;
    const int wid = tid >> 6, lane = tid & 63;
    const int wm = wid >> 1, wn = wid & 1;
    const int m0 = mb * 64, n0 = nb * 64;
    const size_t k0 = (size_t)kz * 1536;

    const int sr = tid >> 2;
    const int sk = (tid & 3) * 8;
    const int kf = (lane >> 4) * 8;
    const int rf = lane & 15;

    f32x4 zero = {0.f, 0.f, 0.f, 0.f};
    f32x4 acc00 = zero, acc01 = zero, acc10 = zero, acc11 = zero;

    for (int ks = 0; ks < 48; ks++) {
        const size_t kc = k0 + (size_t)ks * 32;
        *(short8v*)&a_s[sr][sk] = *(const short8v*)&featb[(size_t)(m0 + sr) * FEAT_F + kc + sk];
        *(short8v*)&b_s[sr][sk] = *(const short8v*)&lwT[(size_t)(n0 + sr) * FEAT_F + kc + sk];
        __syncthreads();
        short8v af0 = *(const short8v*)&a_s[wm * 32 + rf][kf];
        short8v af1 = *(const short8v*)&a_s[wm * 32 + 16 + rf][kf];
        short8v bf0 = *(const short8v*)&b_s[wn * 32 + rf][kf];
        short8v bf1 = *(const short8v*)&b_s[wn * 32 + 16 + rf][kf];
        acc00 = __builtin_amdgcn_mfma_f32_16x16x32_bf16(af0, bf0, acc00, 0, 0, 0);
        acc01 = __builtin_amdgcn_mfma_f32_16x16x32_bf16(af0, bf1, acc01, 0, 0, 0);
        acc10 = __builtin_amdgcn_mfma_f32_16x16x32_bf16(af1, bf0, acc10, 0, 0, 0);
        acc11 = __builtin_amdgcn_mfma_f32_16x16x32_bf16(af1, bf1, acc11, 0, 0, 0);
        __syncthreads();
    }
    float* outz = hacc8 + (size_t)kz * 1024 * 512;
    const int rbase = m0 + wm * 32 + (lane >> 4) * 4;
    const int cbase = n0 + wn * 32 + rf;
    #pragma unroll
    for (int r = 0; r < 4; r++) {
        outz[(size_t)(rbase + r) * 512 + cbase]           = acc00[r];
        outz[(size_t)(rbase + r) * 512 + cbase + 16]      = acc01[r];
        outz[(size_t)(rbase + 16 + r) * 512 + cbase]      = acc10[r];
        outz[(size_t)(rbase + 16 + r) * 512 + cbase + 16] = acc11[r];
    }
}

// ---------------- sum split-K + bias + relu + score dot ----------------
__global__ __launch_bounds__(256)
void score_kernel(const float* __restrict__ hacc8, const float* __restrict__ lb,
                  const float* __restrict__ sw, const float* __restrict__ sb,
                  float* __restrict__ outp)
{
    const int b = blockIdx.x, tid = threadIdx.x;
    float v = 0.f;
    for (int j = tid; j < 512; j += 256) {
        float s = lb[j];
        #pragma unroll
        for (int z = 0; z < 8; z++)
            s += hacc8[((size_t)z * 1024 + b) * 512 + j];
        v += fmaxf(s, 0.f) * sw[j];
    }
    #pragma unroll
    for (int off = 32; off > 0; off >>= 1) v += __shfl_down(v, off);
    __shared__ float red[4];
    if ((tid & 63) == 0) red[tid >> 6] = v;
    __syncthreads();
    if (tid == 0) outp[b] = red[0] + red[1] + red[2] + red[3] + sb[0];
}

extern "C" void kernel_launch(void* const* d_in, const int* in_sizes, int n_in,
                              void* d_out, int out_size, void* d_ws, size_t ws_size,
                              hipStream_t stream)
{
    const float* x_q = (const float*)d_in[0];
    const float* x_c = (const float*)d_in[1];
    const float* gw[3] = {(const float*)d_in[2], (const float*)d_in[4], (const float*)d_in[6]};
    const float* gb[3] = {(const float*)d_in[3], (const float*)d_in[5], (const float*)d_in[7]};
    const float* c1w = (const float*)d_in[8];
    const float* c1b = (const float*)d_in[9];
    const float* c2w = (const float*)d_in[10];
    const float* c2b = (const float*)d_in[11];
    const float* lw  = (const float*)d_in[12];
    const float* lb  = (const float*)d_in[13];
    const float* sw  = (const float*)d_in[14];
    const float* sb  = (const float*)d_in[15];
    const int* eq = (const int*)d_in[16];
    const int* ec = (const int*)d_in[17];

    // Workspace: 172 MB (simsb eliminated by sims->conv fusion).
    char* p = (char*)d_ws;
    ushort* hq0 = (ushort*)p; p += (size_t)NB * 8192 * 2;
    ushort* hc0 = (ushort*)p; p += (size_t)NB * 8192 * 2;
    ushort* hq1 = (ushort*)p; p += (size_t)NB * 8192 * 2;
    ushort* hc1 = (ushort*)p; p += (size_t)NB * 8192 * 2;
    ushort* hq2 = (ushort*)p; p += (size_t)NB * 8192 * 2;
    ushort* hc2 = (ushort*)p; p += (size_t)NB * 8192 * 2;
    ushort* Aqb = (ushort*)p; p += (size_t)NB * 4096 * 2;
    ushort* Acb = (ushort*)p; p += (size_t)NB * 4096 * 2;
    ushort* wtb = (ushort*)p; p += (size_t)3 * ND * ND * 2;
    float* hacc8 = (float*)p; p += (size_t)8 * NB * 512 * 4;
    ushort* featb = (ushort*)p; p += (size_t)NB * FEAT_F * 2;
    ushort* lwT   = (ushort*)p; p += (size_t)512 * FEAT_F * 2;
    float* outf = (float*)d_out;

    const int* esq = eq;
    const int* edq = eq + (size_t)NB * NE;
    const int* esc = ec;
    const int* edc = ec + (size_t)NB * NE;

    adj_kernel<<<dim3(NB, 2), 256, 0, stream>>>(esq, edq, esc, edc, Aqb, Acb);
    castw_kernel<<<3, 256, 0, stream>>>(gw[0], gw[1], gw[2], wtb);
    cast_lwT_kernel<<<dim3(FEAT_F / 32, 512 / 32), 256, 0, stream>>>(lw, lwT);

    gcn_mfma_kernel<<<dim3(NB, 2), 256, 0, stream>>>(x_q, x_c, Aqb, Acb, wtb,
                                                     gb[0], hq0, hc0, 1);
    gcn_mfma_kernel<<<dim3(NB, 2), 256, 0, stream>>>(hq0, hc0, Aqb, Acb, wtb + ND * ND,
                                                     gb[1], hq1, hc1, 0);
    gcn_mfma_kernel<<<dim3(NB, 2), 256, 0, stream>>>(hq1, hc1, Aqb, Acb, wtb + 2 * ND * ND,
                                                     gb[2], hq2, hc2, 0);

    conv_kernel<<<dim3(NB, 3), 256, 0, stream>>>(hq0, hc0, hq1, hc1, hq2, hc2,
                                                 c1w, c1b, c2w, c2b, featb);

    lin_mfma_kernel<<<dim3(8, 16, 8), 256, 0, stream>>>(featb, lwT, hacc8);
    score_kernel<<<NB, 256, 0, stream>>>(hacc8, lb, sw, sb, outf);
}

// Round 14
// 389.193 us; speedup vs baseline: 1.1267x; 1.1267x over previous
//
#include <hip/hip_runtime.h>

constexpr int NB = 1024;   // graphs
constexpr int NN = 64;     // nodes per graph
constexpr int ND = 128;    // feature dim (D == G == 128)
constexpr int NE = 512;    // edges per graph
constexpr int FEAT_F = 12288;  // 3*16*16*16

typedef __attribute__((ext_vector_type(8))) short short8v;   // 8 bf16 (4 VGPRs)
typedef __attribute__((ext_vector_type(4))) float f32x4;
typedef __fp16 h2v __attribute__((ext_vector_type(2)));      // matches cvt_pkrtz/fdot2

__device__ inline ushort f2bf(float x) {                      // fp32 -> bf16 RNE
    unsigned u = __float_as_uint(x);
    u += 0x7FFFu + ((u >> 16) & 1u);
    return (ushort)(u >> 16);
}

// ---------------- build normalized adjacency Â (bf16) per (graph, side) ----------------
__global__ __launch_bounds__(256)
void adj_kernel(const int* __restrict__ esq, const int* __restrict__ edq,
                const int* __restrict__ esc, const int* __restrict__ edc,
                ushort* __restrict__ Aq, ushort* __restrict__ Ac)
{
    __shared__ float A[NN * NN];
    __shared__ float dis[NN];
    const int b = blockIdx.x, side = blockIdx.y, tid = threadIdx.x;
    const int* es = side ? esc : esq;
    const int* ed = side ? edc : edq;
    ushort* Aout = side ? Ac : Aq;

    for (int i = tid; i < NN * NN; i += 256) A[i] = 0.f;
    __syncthreads();
    for (int e = tid; e < NE; e += 256) {
        const int s = es[b * NE + e] & (NN - 1);
        const int d = ed[b * NE + e] & (NN - 1);
        atomicAdd(&A[d * NN + s], 1.0f);
    }
    __syncthreads();
    if (tid < NN) {
        float sum = 1.0f;                       // self loop
        for (int s = 0; s < NN; s++) sum += A[tid * NN + s];
        dis[tid] = rsqrtf(sum);
    }
    __syncthreads();
    for (int i = tid; i < NN * NN; i += 256) {
        const int d = i >> 6, s = i & 63;
        float v = A[i];
        if (d == s) v += 1.0f;                  // self loop
        Aout[(size_t)b * (NN * NN) + i] = f2bf(dis[d] * v * dis[s]);
    }
}

// ---------------- cast+transpose gcn weights: wtb[l][f][k] = bf16(W_l[k][f]) ----------------
__global__ __launch_bounds__(256)
void castw_kernel(const float* __restrict__ w0, const float* __restrict__ w1,
                  const float* __restrict__ w2, ushort* __restrict__ wtb)
{
    const float* W = blockIdx.x == 0 ? w0 : (blockIdx.x == 1 ? w1 : w2);
    ushort* out = wtb + (size_t)blockIdx.x * ND * ND;
    for (int i = threadIdx.x; i < ND * ND; i += 256) {
        const int f = i >> 7, k = i & 127;
        out[i] = f2bf(W[k * ND + f]);
    }
}

// ---------------- GCN layer via MFMA (r9 staged version — known-good) ----------------
__global__ __launch_bounds__(256)
void gcn_mfma_kernel(const void* __restrict__ hq_in, const void* __restrict__ hc_in,
                     const ushort* __restrict__ Aqb, const ushort* __restrict__ Acb,
                     const ushort* __restrict__ wt_l, const float* __restrict__ bias,
                     ushort* __restrict__ outq, ushort* __restrict__ outc, int first)
{
    __shared__ ushort ht[64][132];     // H bf16 (relu'd), 16.9KB
    __shared__ ushort wt[128][132];    // W^T [f][k], 33.8KB
    __shared__ ushort mT[128][68];     // M^T [f][s], 17.4KB
    __shared__ ushort as_[64][68];     // Â [d][s], 8.7KB

    const int b = blockIdx.x, side = blockIdx.y, tid = threadIdx.x;
    const int lane = tid & 63, w = tid >> 6;
    const int q = lane >> 4, rf = lane & 15;

    const ushort* Ab = (side ? Acb : Aqb) + (size_t)b * 4096;
    ushort* outp = (side ? outc : outq) + (size_t)b * 8192;

    {
        const int sr = tid >> 2, sc = (tid & 3) * 32;
        if (first) {
            const float* hin = (const float*)(side ? hc_in : hq_in) + (size_t)b * 8192 + sr * 128 + sc;
            #pragma unroll
            for (int j = 0; j < 4; j++) {
                const float4 v0 = *(const float4*)&hin[8 * j];
                const float4 v1 = *(const float4*)&hin[8 * j + 4];
                *(ushort4*)&ht[sr][sc + 8 * j]     = make_ushort4(f2bf(v0.x), f2bf(v0.y), f2bf(v0.z), f2bf(v0.w));
                *(ushort4*)&ht[sr][sc + 8 * j + 4] = make_ushort4(f2bf(v1.x), f2bf(v1.y), f2bf(v1.z), f2bf(v1.w));
            }
        } else {
            const ushort* hin = (const ushort*)(side ? hc_in : hq_in) + (size_t)b * 8192 + sr * 128 + sc;
            #pragma unroll
            for (int j = 0; j < 4; j++) {
                short8v v = *(const short8v*)&hin[8 * j];
                #pragma unroll
                for (int e = 0; e < 8; e++) {
                    const ushort u = (ushort)v[e];
                    v[e] = (short)((u & 0x8000u) ? 0u : u);   // relu(bf16)
                }
                *(short8v*)&ht[sr][sc + 8 * j] = v;
            }
        }
    }
    {
        const int wr = tid >> 1, wc = (tid & 1) * 64;
        const ushort* src = wt_l + wr * 128 + wc;
        #pragma unroll
        for (int j = 0; j < 8; j++)
            *(short8v*)&wt[wr][wc + 8 * j] = *(const short8v*)&src[8 * j];
    }
    {
        const int ar = tid >> 2, ac = (tid & 3) * 16;
        const ushort* src = Ab + ar * 64 + ac;
        *(short8v*)&as_[ar][ac]     = *(const short8v*)&src[0];
        *(short8v*)&as_[ar][ac + 8] = *(const short8v*)&src[8];
    }
    __syncthreads();

    {
        f32x4 acc1[8];
        #pragma unroll
        for (int cb = 0; cb < 8; cb++) acc1[cb] = f32x4{0.f, 0.f, 0.f, 0.f};
        short8v af[4];
        #pragma unroll
        for (int ks = 0; ks < 4; ks++)
            af[ks] = *(const short8v*)&ht[16 * w + rf][32 * ks + 8 * q];
        #pragma unroll
        for (int cb = 0; cb < 8; cb++)
            #pragma unroll
            for (int ks = 0; ks < 4; ks++) {
                const short8v bf = *(const short8v*)&wt[16 * cb + rf][32 * ks + 8 * q];
                acc1[cb] = __builtin_amdgcn_mfma_f32_16x16x32_bf16(af[ks], bf, acc1[cb], 0, 0, 0);
            }
        #pragma unroll
        for (int cb = 0; cb < 8; cb++)
            *(ushort4*)&mT[16 * cb + rf][16 * w + 4 * q] =
                make_ushort4(f2bf(acc1[cb][0]), f2bf(acc1[cb][1]), f2bf(acc1[cb][2]), f2bf(acc1[cb][3]));
    }
    __syncthreads();

    {
        f32x4 acc2[8];
        #pragma unroll
        for (int cb = 0; cb < 8; cb++) acc2[cb] = f32x4{0.f, 0.f, 0.f, 0.f};
        short8v af2[2];
        #pragma unroll
        for (int ks = 0; ks < 2; ks++)
            af2[ks] = *(const short8v*)&as_[16 * w + rf][32 * ks + 8 * q];
        #pragma unroll
        for (int cb = 0; cb < 8; cb++)
            #pragma unroll
            for (int ks = 0; ks < 2; ks++) {
                const short8v bf2 = *(const short8v*)&mT[16 * cb + rf][32 * ks + 8 * q];
                acc2[cb] = __builtin_amdgcn_mfma_f32_16x16x32_bf16(af2[ks], bf2, acc2[cb], 0, 0, 0);
            }
        #pragma unroll
        for (int cb = 0; cb < 8; cb++) {
            const float bb = bias[16 * cb + rf];
            #pragma unroll
            for (int r = 0; r < 4; r++)
                outp[(16 * w + 4 * q + r) * 128 + 16 * cb + rf] = f2bf(acc2[cb][r] + bb);
        }
    }
}

// ---------------- fused sims + conv1 (f16 dot2) + conv2 (bf16 MFMA) ----------------
__global__ __launch_bounds__(256)
void conv_kernel(const ushort* __restrict__ hq0, const ushort* __restrict__ hc0,
                 const ushort* __restrict__ hq1, const ushort* __restrict__ hc1,
                 const ushort* __restrict__ hq2, const ushort* __restrict__ hc2,
                 const float* __restrict__ c1w, const float* __restrict__ c1b,
                 const float* __restrict__ c2w, const float* __restrict__ c2b,
                 ushort* __restrict__ featb)
{
    __shared__ float img[68 * 68];          // 18.5KB, 64x64 padded by 2
    __shared__ ushort p1b[36 * 36 * 8];     // 20.7KB
    __shared__ ushort w2s[16][232];         // 7.4KB

    const int b = blockIdx.x, l = blockIdx.y, tid = threadIdx.x;
    const int lane = tid & 63, wid = tid >> 6;
    const int q = lane >> 4, rf = lane & 15;

    const ushort* hq = (l == 0 ? hq0 : (l == 1 ? hq1 : hq2)) + (size_t)b * 8192;
    const ushort* hc = (l == 0 ? hc0 : (l == 1 ? hc1 : hc2)) + (size_t)b * 8192;

    for (int i = tid; i < 68 * 68; i += 256) img[i] = 0.f;
    for (int i = tid; i < 36 * 36 * 8 / 2; i += 256) ((uint*)p1b)[i] = 0u;
    for (int i = tid; i < 16 * 224; i += 256) {
        const int co = i / 224, k = i - co * 224;
        const int tap = k >> 3, ci = k & 7;
        w2s[co][k] = (tap < 25) ? f2bf(c2w[l * 3200 + co * 200 + ci * 25 + tap])
                                : (ushort)0;
    }
    __syncthreads();

    // ---- sims MFMA: wave computes S rows 16*wid..16*wid+15, writes img interior ----
    {
        short8v afq[4];
        #pragma unroll
        for (int ks = 0; ks < 4; ks++)
            afq[ks] = *(const short8v*)&hq[(size_t)(16 * wid + rf) * 128 + 32 * ks + 8 * q];
        #pragma unroll
        for (int cb = 0; cb < 4; cb++) {
            f32x4 acc = {0.f, 0.f, 0.f, 0.f};
            #pragma unroll
            for (int ks = 0; ks < 4; ks++) {
                const short8v bf = *(const short8v*)&hc[(size_t)(16 * cb + rf) * 128 + 32 * ks + 8 * q];
                acc = __builtin_amdgcn_mfma_f32_16x16x32_bf16(afq[ks], bf, acc, 0, 0, 0);
            }
            #pragma unroll
            for (int r = 0; r < 4; r++)
                img[(16 * wid + 4 * q + r + 2) * 68 + (16 * cb + rf + 2)] = acc[r];
        }
    }
    __syncthreads();

    // ---- conv1: thread owns 2x2 POOLED outputs at (2by+jy, 2bx+jx); 8x8 patch ----
    {
        const int by = tid >> 4, bx = tid & 15;
        float mv[2][2][8];                   // [jy][jx][cout] pooled+relu'd results
#if __has_builtin(__builtin_amdgcn_fdot2)
        h2v pe[8][4], po[8][4];
        #pragma unroll
        for (int r = 0; r < 8; r++) {
            float x[8];
            #pragma unroll
            for (int c2 = 0; c2 < 4; c2++) {
                const float2 v = *(const float2*)&img[(4 * by + r) * 68 + 4 * bx + 2 * c2];
                x[2 * c2] = v.x; x[2 * c2 + 1] = v.y;
            }
            #pragma unroll
            for (int m = 0; m < 4; m++) {
                pe[r][m] = __builtin_amdgcn_cvt_pkrtz(x[2 * m], x[2 * m + 1]);
                po[r][m] = __builtin_amdgcn_cvt_pkrtz(x[2 * m + 1], (m < 3) ? x[2 * m + 2] : x[7]);
            }
        }
        for (int c = 0; c < 8; c++) {
            h2v wp[5][3];
            #pragma unroll
            for (int ky = 0; ky < 5; ky++) {
                const float w0 = c1w[l * 200 + c * 25 + 5 * ky];
                const float w1 = c1w[l * 200 + c * 25 + 5 * ky + 1];
                const float w2 = c1w[l * 200 + c * 25 + 5 * ky + 2];
                const float w3 = c1w[l * 200 + c * 25 + 5 * ky + 3];
                const float w4 = c1w[l * 200 + c * 25 + 5 * ky + 4];
                wp[ky][0] = __builtin_amdgcn_cvt_pkrtz(w0, w1);
                wp[ky][1] = __builtin_amdgcn_cvt_pkrtz(w2, w3);
                wp[ky][2] = __builtin_amdgcn_cvt_pkrtz(w4, 0.f);
            }
            const float bb = c1b[l * 8 + c];
            #pragma unroll
            for (int jy = 0; jy < 2; jy++)
                #pragma unroll
                for (int jx = 0; jx < 2; jx++) {
                    float mm = 0.f;
                    #pragma unroll
                    for (int dy = 0; dy < 2; dy++)
                        #pragma unroll
                        for (int dx = 0; dx < 2; dx++) {
                            const int Y = 2 * jy + dy, X = 2 * jx + dx, m0 = X >> 1;
                            float a = bb;
                            #pragma unroll
                            for (int ky = 0; ky < 5; ky++) {
                                if (X & 1) {
                                    a = __builtin_amdgcn_fdot2(po[Y + ky][m0],     wp[ky][0], a, false);
                                    a = __builtin_amdgcn_fdot2(po[Y + ky][m0 + 1], wp[ky][1], a, false);
                                    a = __builtin_amdgcn_fdot2(po[Y + ky][m0 + 2], wp[ky][2], a, false);
                                } else {
                                    a = __builtin_amdgcn_fdot2(pe[Y + ky][m0],     wp[ky][0], a, false);
                                    a = __builtin_amdgcn_fdot2(pe[Y + ky][m0 + 1], wp[ky][1], a, false);
                                    a = __builtin_amdgcn_fdot2(pe[Y + ky][m0 + 2], wp[ky][2], a, false);
                                }
                            }
                            mm = fmaxf(mm, a);
                        }
                    mv[jy][jx][c] = mm;
                }
        }
#else
        float pt[8][8];
        #pragma unroll
        for (int r = 0; r < 8; r++)
            #pragma unroll
            for (int c2 = 0; c2 < 4; c2++) {
                const float2 v = *(const float2*)&img[(4 * by + r) * 68 + 4 * bx + 2 * c2];
                pt[r][2 * c2] = v.x; pt[r][2 * c2 + 1] = v.y;
            }
        for (int c = 0; c < 8; c++) {
            float wr[25];
            #pragma unroll
            for (int t = 0; t < 25; t++) wr[t] = c1w[l * 200 + c * 25 + t];
            const float bb = c1b[l * 8 + c];
            #pragma unroll
            for (int jy = 0; jy < 2; jy++)
                #pragma unroll
                for (int jx = 0; jx < 2; jx++) {
                    float mm = 0.f;
                    #pragma unroll
                    for (int dy = 0; dy < 2; dy++)
                        #pragma unroll
                        for (int dx = 0; dx < 2; dx++) {
                            float a = bb;
                            #pragma unroll
                            for (int ky = 0; ky < 5; ky++)
                                #pragma unroll
                                for (int kx = 0; kx < 5; kx++)
                                    a += pt[2 * jy + dy + ky][2 * jx + dx + kx] * wr[ky * 5 + kx];
                            mm = fmaxf(mm, a);
                        }
                    mv[jy][jx][c] = mm;
                }
        }
#endif
        #pragma unroll
        for (int jy = 0; jy < 2; jy++)
            #pragma unroll
            for (int jx = 0; jx < 2; jx++) {
                const int pos = (2 * by + jy + 2) * 36 + (2 * bx + jx + 2);
                *(ushort4*)&p1b[pos * 8] =
                    make_ushort4(f2bf(mv[jy][jx][0]), f2bf(mv[jy][jx][1]),
                                 f2bf(mv[jy][jx][2]), f2bf(mv[jy][jx][3]));
                *(ushort4*)&p1b[pos * 8 + 4] =
                    make_ushort4(f2bf(mv[jy][jx][4]), f2bf(mv[jy][jx][5]),
                                 f2bf(mv[jy][jx][6]), f2bf(mv[jy][jx][7]));
            }
    }
    __syncthreads();

    // ---- conv2 MFMA: wave handles y-pairs r = wid+4t ----
    short8v bf[7];
    #pragma unroll
    for (int ks = 0; ks < 7; ks++)
        bf[ks] = *(const short8v*)&w2s[rf][32 * ks + 8 * q];
    const float bb2 = c2b[l * 16 + rf];

    for (int t = 0; t < 4; t++) {
        const int r = wid + 4 * t;
        f32x4 acc00 = {0.f,0.f,0.f,0.f}, acc01 = acc00, acc10 = acc00, acc11 = acc00;
        #pragma unroll
        for (int ks = 0; ks < 7; ks++) {
            const int tap = 4 * ks + q;
            const int dy = tap / 5, dx = tap - 5 * dy;
            const bool dum = tap >= 25;
            const int row0 = dum ? 35 : (2 * r + dy);
            const int row1 = dum ? 35 : (2 * r + 1 + dy);
            const int cb   = (dum ? 0 : dx) + rf;
            const short8v a00 = *(const short8v*)&p1b[(row0 * 36 + cb) * 8];
            const short8v a01 = *(const short8v*)&p1b[(row0 * 36 + cb + 16) * 8];
            const short8v a10 = *(const short8v*)&p1b[(row1 * 36 + cb) * 8];
            const short8v a11 = *(const short8v*)&p1b[(row1 * 36 + cb + 16) * 8];
            acc00 = __builtin_amdgcn_mfma_f32_16x16x32_bf16(a00, bf[ks], acc00, 0, 0, 0);
            acc01 = __builtin_amdgcn_mfma_f32_16x16x32_bf16(a01, bf[ks], acc01, 0, 0, 0);
            acc10 = __builtin_amdgcn_mfma_f32_16x16x32_bf16(a10, bf[ks], acc10, 0, 0, 0);
            acc11 = __builtin_amdgcn_mfma_f32_16x16x32_bf16(a11, bf[ks], acc11, 0, 0, 0);
        }
        const float v0 = fmaxf(fmaxf(fmaxf(acc00[0], acc00[1]), fmaxf(acc10[0], acc10[1])) + bb2, 0.f);
        const float v1 = fmaxf(fmaxf(fmaxf(acc00[2], acc00[3]), fmaxf(acc10[2], acc10[3])) + bb2, 0.f);
        const float v2 = fmaxf(fmaxf(fmaxf(acc01[0], acc01[1]), fmaxf(acc11[0], acc11[1])) + bb2, 0.f);
        const float v3 = fmaxf(fmaxf(fmaxf(acc01[2], acc01[3]), fmaxf(acc11[2], acc11[3])) + bb2, 0.f);
        const size_t base = (size_t)b * FEAT_F + ((size_t)l * 16 + rf) * 256 + r * 16;
        featb[base + 2 * q]         = f2bf(v0);
        featb[base + 2 * q + 1]     = f2bf(v1);
        featb[base + 8 + 2 * q]     = f2bf(v2);
        featb[base + 8 + 2 * q + 1] = f2bf(v3);
    }
}

// ---------------- cast + transpose lw (12288x512) -> lwT bf16 (512x12288) ----------------
__global__ __launch_bounds__(256)
void cast_lwT_kernel(const float* __restrict__ lw, ushort* __restrict__ lwT)
{
    __shared__ ushort t[32][34];
    const int kb = blockIdx.x * 32, nb2 = blockIdx.y * 32;
    const int x = threadIdx.x & 31, y = threadIdx.x >> 5;
    #pragma unroll
    for (int j = 0; j < 4; j++) {
        const int yy = y + 8 * j;
        t[x][yy] = f2bf(lw[(size_t)(kb + yy) * 512 + nb2 + x]);
    }
    __syncthreads();
    #pragma unroll
    for (int j = 0; j < 4; j++) {
        const int yy = y + 8 * j;
        lwT[(size_t)(nb2 + yy) * FEAT_F + kb + x] = t[yy][x];
    }
}

// ---------------- linear via MFMA: hacc8[kz] = feat_tile @ lw_tile ----------------
__global__ __launch_bounds__(256)
void lin_mfma_kernel(const ushort* __restrict__ featb, const ushort* __restrict__ lwT,
                     float* __restrict__ hacc8)
{
    __shared__ ushort a_s[64][40];
    __shared__ ushort b_s[64][40];
    const int nb = blockIdx.x, mb = blockIdx.y, kz = blockIdx.z;
    const int tid = threadIdx.x;
    const int wid = tid >> 6, lane = tid & 63;
    const int wm = wid >> 1, wn = wid & 1;
    const int m0 = mb * 64, n0 = nb * 64;
    const size_t k0 = (size_t)kz * 1536;

    const int sr = tid >> 2;
    const int sk = (tid & 3) * 8;
    const int kf = (lane >> 4) * 8;
    const int rf = lane & 15;

    f32x4 zero = {0.f, 0.f, 0.f, 0.f};
    f32x4 acc00 = zero, acc01 = zero, acc10 = zero, acc11 = zero;

    for (int ks = 0; ks < 48; ks++) {
        const size_t kc = k0 + (size_t)ks * 32;
        *(short8v*)&a_s[sr][sk] = *(const short8v*)&featb[(size_t)(m0 + sr) * FEAT_F + kc + sk];
        *(short8v*)&b_s[sr][sk] = *(const short8v*)&lwT[(size_t)(n0 + sr) * FEAT_F + kc + sk];
        __syncthreads();
        short8v af0 = *(const short8v*)&a_s[wm * 32 + rf][kf];
        short8v af1 = *(const short8v*)&a_s[wm * 32 + 16 + rf][kf];
        short8v bf0 = *(const short8v*)&b_s[wn * 32 + rf][kf];
        short8v bf1 = *(const short8v*)&b_s[wn * 32 + 16 + rf][kf];
        acc00 = __builtin_amdgcn_mfma_f32_16x16x32_bf16(af0, bf0, acc00, 0, 0, 0);
        acc01 = __builtin_amdgcn_mfma_f32_16x16x32_bf16(af0, bf1, acc01, 0, 0, 0);
        acc10 = __builtin_amdgcn_mfma_f32_16x16x32_bf16(af1, bf0, acc10, 0, 0, 0);
        acc11 = __builtin_amdgcn_mfma_f32_16x16x32_bf16(af1, bf1, acc11, 0, 0, 0);
        __syncthreads();
    }
    float* outz = hacc8 + (size_t)kz * 1024 * 512;
    const int rbase = m0 + wm * 32 + (lane >> 4) * 4;
    const int cbase = n0 + wn * 32 + rf;
    #pragma unroll
    for (int r = 0; r < 4; r++) {
        outz[(size_t)(rbase + r) * 512 + cbase]           = acc00[r];
        outz[(size_t)(rbase + r) * 512 + cbase + 16]      = acc01[r];
        outz[(size_t)(rbase + 16 + r) * 512 + cbase]      = acc10[r];
        outz[(size_t)(rbase + 16 + r) * 512 + cbase + 16] = acc11[r];
    }
}

// ---------------- sum split-K + bias + relu + score dot ----------------
__global__ __launch_bounds__(256)
void score_kernel(const float* __restrict__ hacc8, const float* __restrict__ lb,
                  const float* __restrict__ sw, const float* __restrict__ sb,
                  float* __restrict__ outp)
{
    const int b = blockIdx.x, tid = threadIdx.x;
    float v = 0.f;
    for (int j = tid; j < 512; j += 256) {
        float s = lb[j];
        #pragma unroll
        for (int z = 0; z < 8; z++)
            s += hacc8[((size_t)z * 1024 + b) * 512 + j];
        v += fmaxf(s, 0.f) * sw[j];
    }
    #pragma unroll
    for (int off = 32; off > 0; off >>= 1) v += __shfl_down(v, off);
    __shared__ float red[4];
    if ((tid & 63) == 0) red[tid >> 6] = v;
    __syncthreads();
    if (tid == 0) outp[b] = red[0] + red[1] + red[2] + red[3] + sb[0];
}

extern "C" void kernel_launch(void* const* d_in, const int* in_sizes, int n_in,
                              void* d_out, int out_size, void* d_ws, size_t ws_size,
                              hipStream_t stream)
{
    const float* x_q = (const float*)d_in[0];
    const float* x_c = (const float*)d_in[1];
    const float* gw[3] = {(const float*)d_in[2], (const float*)d_in[4], (const float*)d_in[6]};
    const float* gb[3] = {(const float*)d_in[3], (const float*)d_in[5], (const float*)d_in[7]};
    const float* c1w = (const float*)d_in[8];
    const float* c1b = (const float*)d_in[9];
    const float* c2w = (const float*)d_in[10];
    const float* c2b = (const float*)d_in[11];
    const float* lw  = (const float*)d_in[12];
    const float* lb  = (const float*)d_in[13];
    const float* sw  = (const float*)d_in[14];
    const float* sb  = (const float*)d_in[15];
    const int* eq = (const int*)d_in[16];
    const int* ec = (const int*)d_in[17];

    // Workspace: 172 MB (simsb eliminated by sims->conv fusion).
    char* p = (char*)d_ws;
    ushort* hq0 = (ushort*)p; p += (size_t)NB * 8192 * 2;
    ushort* hc0 = (ushort*)p; p += (size_t)NB * 8192 * 2;
    ushort* hq1 = (ushort*)p; p += (size_t)NB * 8192 * 2;
    ushort* hc1 = (ushort*)p; p += (size_t)NB * 8192 * 2;
    ushort* hq2 = (ushort*)p; p += (size_t)NB * 8192 * 2;
    ushort* hc2 = (ushort*)p; p += (size_t)NB * 8192 * 2;
    ushort* Aqb = (ushort*)p; p += (size_t)NB * 4096 * 2;
    ushort* Acb = (ushort*)p; p += (size_t)NB * 4096 * 2;
    ushort* wtb = (ushort*)p; p += (size_t)3 * ND * ND * 2;
    float* hacc8 = (float*)p; p += (size_t)8 * NB * 512 * 4;
    ushort* featb = (ushort*)p; p += (size_t)NB * FEAT_F * 2;
    ushort* lwT   = (ushort*)p; p += (size_t)512 * FEAT_F * 2;
    float* outf = (float*)d_out;

    const int* esq = eq;
    const int* edq = eq + (size_t)NB * NE;
    const int* esc = ec;
    const int* edc = ec + (size_t)NB * NE;

    adj_kernel<<<dim3(NB, 2), 256, 0, stream>>>(esq, edq, esc, edc, Aqb, Acb);
    castw_kernel<<<3, 256, 0, stream>>>(gw[0], gw[1], gw[2], wtb);
    cast_lwT_kernel<<<dim3(FEAT_F / 32, 512 / 32), 256, 0, stream>>>(lw, lwT);

    gcn_mfma_kernel<<<dim3(NB, 2), 256, 0, stream>>>(x_q, x_c, Aqb, Acb, wtb,
                                                     gb[0], hq0, hc0, 1);
    gcn_mfma_kernel<<<dim3(NB, 2), 256, 0, stream>>>(hq0, hc0, Aqb, Acb, wtb + ND * ND,
                                                     gb[1], hq1, hc1, 0);
    gcn_mfma_kernel<<<dim3(NB, 2), 256, 0, stream>>>(hq1, hc1, Aqb, Acb, wtb + 2 * ND * ND,
                                                     gb[2], hq2, hc2, 0);

    conv_kernel<<<dim3(NB, 3), 256, 0, stream>>>(hq0, hc0, hq1, hc1, hq2, hc2,
                                                 c1w, c1b, c2w, c2b, featb);

    lin_mfma_kernel<<<dim3(8, 16, 8), 256, 0, stream>>>(featb, lwT, hacc8);
    score_kernel<<<NB, 256, 0, stream>>>(hacc8, lb, sw, sb, outf);
}